// Round 5
// baseline (287.338 us; speedup 1.0000x reference)
//
#include <hip/hip_runtime.h>
#include <hip/hip_bf16.h>
#include <math.h>

#define NN 13
#define NC 26
#define VOC 10000
#define E 64
#define LAYERS 3
#define F 39
#define P 72    // S pitch (ushorts), 144B rows
#define VP 56   // Vt pitch (ushorts), 112B rows (16B-aligned)
#define S_SZ  (48 * P)    // 3456 ushorts
#define VT_SZ (65 * VP)   // 3640 ushorts (row 64 = overrun pad)

typedef float f32x4 __attribute__((ext_vector_type(4)));
typedef short s16x8 __attribute__((ext_vector_type(8)));

__device__ __forceinline__ ushort f2bf_rne(float f) {
    uint u = __builtin_bit_cast(uint, f);
    u = (u + 0x7fffu + ((u >> 16) & 1u)) >> 16;
    return (ushort)u;
}
__device__ __forceinline__ ushort fb(float f) {   // fuses to v_cvt_pk_bf16_f32
    return __builtin_bit_cast(ushort, __float2bfloat16(f));
}
__device__ __forceinline__ float bf2f(ushort h) {
    uint u = ((uint)h) << 16;
    return __builtin_bit_cast(float, u);
}
__device__ __forceinline__ void pack4(ushort* dst, f32x4 v) {
    ushort4 p;
    p.x = fb(v[0]); p.y = fb(v[1]); p.z = fb(v[2]); p.w = fb(v[3]);
    *(ushort4*)dst = p;
}

// ---- one-shot fp32 -> bf16 weight conversion into d_ws ----
__global__ void cvt_weights(const float* __restrict__ wq, const float* __restrict__ wk,
                            const float* __restrict__ wv, const float* __restrict__ wo,
                            const float* __restrict__ wr, ushort* __restrict__ outw) {
    int i = blockIdx.x * 256 + threadIdx.x;
    if (i >= 5 * 3 * 4096) return;
    int m = i / 12288, jj = i - m * 12288;
    const float* src = (m == 0) ? wq : (m == 1) ? wk : (m == 2) ? wv : (m == 3) ? wo : wr;
    outw[i] = f2bf_rne(src[jj]);
}

__global__ __launch_bounds__(64, 2) void autoint_mfma(
    const float* __restrict__ num, const int* __restrict__ cat,
    const float* __restrict__ Wnum, const float* __restrict__ bnum,
    const float* __restrict__ tabs, const ushort* __restrict__ wsw,
    const float* __restrict__ Wf, const float* __restrict__ bfin,
    float* __restrict__ out)
{
    __shared__ __align__(16) ushort smem[2 * S_SZ + 2 * VT_SZ];  // 28384 B

    const int l = threadIdx.x;
    const int j = l & 15;
    const int g = l >> 4;
    const long s0 = 2 * (long)blockIdx.x;
    const long s1 = s0 + 1;

    ushort4 z4; z4.x = z4.y = z4.z = z4.w = 0;

    // zero Vt pad: cols 48..55 for rows 0..63, plus whole row 64 (overrun target)
    #pragma unroll
    for (int sp = 0; sp < 2; ++sp) {
        ushort* V = smem + 2 * S_SZ + sp * VT_SZ;
        *(ushort4*)&V[l * VP + 48] = z4;
        *(ushort4*)&V[l * VP + 52] = z4;
        if (l < 14) *(ushort4*)&V[64 * VP + 4 * l] = z4;
    }

    // ---------------- embedding (weights shared across the 2 samples) ----------------
    {
        ushort* SA = smem;
        ushort* SB = smem + S_SZ;
        for (int f = 0; f < NN; ++f) {
            float wn = Wnum[f * E + l], bn = bnum[f * E + l];
            SA[f * P + l] = fb(num[s0 * NN + f] * wn + bn);
            SB[f * P + l] = fb(num[s1 * NN + f] * wn + bn);
        }
        for (int c = 0; c < NC; ++c) {
            int ia = cat[s0 * NC + c], ib = cat[s1 * NC + c];
            SA[(NN + c) * P + l] = fb(tabs[((size_t)(c * VOC + ia)) * E + l]);
            SB[(NN + c) * P + l] = fb(tabs[((size_t)(c * VOC + ib)) * E + l]);
        }
        #pragma unroll
        for (int r = F; r < 48; ++r) { SA[r * P + l] = 0; SB[r * P + l] = 0; }
    }
    __syncthreads();

    // x fragments in registers, both samples
    s16x8 xf[2][3][2];
    #pragma unroll
    for (int sp = 0; sp < 2; ++sp)
        #pragma unroll
        for (int nt = 0; nt < 3; ++nt)
            #pragma unroll
            for (int kt = 0; kt < 2; ++kt)
                xf[sp][nt][kt] = *(const s16x8*)&smem[sp * S_SZ + (j + 16 * nt) * P + 8 * g + 32 * kt];

    const float scale = 0.17677669529663687f; // 1/sqrt(32)

    for (int l3 = 0; l3 < LAYERS; ++l3) {
        const ushort* wq = wsw + 0 * 12288 + l3 * 4096;
        const ushort* wk = wsw + 1 * 12288 + l3 * 4096;
        const ushort* wv = wsw + 2 * 12288 + l3 * 4096;
        const ushort* wo = wsw + 3 * 12288 + l3 * 4096;
        const ushort* wr = wsw + 4 * 12288 + l3 * 4096;

        // ---- Q^T = WQ @ x^T (both samples) -> stage -> qB regs ----
        s16x8 qB[2][2][3];   // [sp][h][nt]
        {
            f32x4 qa[2][4][3];
            #pragma unroll
            for (int sp = 0; sp < 2; ++sp)
                #pragma unroll
                for (int mt = 0; mt < 4; ++mt)
                    #pragma unroll
                    for (int nt = 0; nt < 3; ++nt) qa[sp][mt][nt] = (f32x4)0.f;
            #pragma unroll
            for (int kt = 0; kt < 2; ++kt)
                #pragma unroll
                for (int mt = 0; mt < 4; ++mt) {
                    s16x8 aq = *(const s16x8*)&wq[(j + 16 * mt) * E + 8 * g + 32 * kt];
                    #pragma unroll
                    for (int sp = 0; sp < 2; ++sp)
                        #pragma unroll
                        for (int nt = 0; nt < 3; ++nt)
                            qa[sp][mt][nt] = __builtin_amdgcn_mfma_f32_16x16x32_bf16(aq, xf[sp][nt][kt], qa[sp][mt][nt], 0, 0, 0);
                }
            __syncthreads();   // xf LDS reads complete before overwrite
            #pragma unroll
            for (int sp = 0; sp < 2; ++sp)
                #pragma unroll
                for (int mt = 0; mt < 4; ++mt)
                    #pragma unroll
                    for (int nt = 0; nt < 3; ++nt)
                        pack4(&smem[sp * S_SZ + (j + 16 * nt) * P + 16 * mt + 4 * g], qa[sp][mt][nt]);
            __syncthreads();
            #pragma unroll
            for (int sp = 0; sp < 2; ++sp)
                #pragma unroll
                for (int h = 0; h < 2; ++h)
                    #pragma unroll
                    for (int t = 0; t < 3; ++t)
                        qB[sp][h][t] = *(const s16x8*)&smem[sp * S_SZ + (j + 16 * t) * P + 32 * h + 8 * g];
            __syncthreads();
        }

        // ---- K^T = WK @ x^T -> stage in S (stays) ----
        {
            f32x4 ka[2][4][3];
            #pragma unroll
            for (int sp = 0; sp < 2; ++sp)
                #pragma unroll
                for (int mt = 0; mt < 4; ++mt)
                    #pragma unroll
                    for (int nt = 0; nt < 3; ++nt) ka[sp][mt][nt] = (f32x4)0.f;
            #pragma unroll
            for (int kt = 0; kt < 2; ++kt)
                #pragma unroll
                for (int mt = 0; mt < 4; ++mt) {
                    s16x8 ak = *(const s16x8*)&wk[(j + 16 * mt) * E + 8 * g + 32 * kt];
                    #pragma unroll
                    for (int sp = 0; sp < 2; ++sp)
                        #pragma unroll
                        for (int nt = 0; nt < 3; ++nt)
                            ka[sp][mt][nt] = __builtin_amdgcn_mfma_f32_16x16x32_bf16(ak, xf[sp][nt][kt], ka[sp][mt][nt], 0, 0, 0);
                }
            #pragma unroll
            for (int sp = 0; sp < 2; ++sp)
                #pragma unroll
                for (int mt = 0; mt < 4; ++mt)
                    #pragma unroll
                    for (int nt = 0; nt < 3; ++nt)
                        pack4(&smem[sp * S_SZ + (j + 16 * nt) * P + 16 * mt + 4 * g], ka[sp][mt][nt]);
            __syncthreads();
        }

        // ---- V = x @ WV^T -> Vt[dim][key] ----
        {
            f32x4 va[2][3][4];
            #pragma unroll
            for (int sp = 0; sp < 2; ++sp)
                #pragma unroll
                for (int mt = 0; mt < 3; ++mt)
                    #pragma unroll
                    for (int nt = 0; nt < 4; ++nt) va[sp][mt][nt] = (f32x4)0.f;
            #pragma unroll
            for (int kt = 0; kt < 2; ++kt)
                #pragma unroll
                for (int nt = 0; nt < 4; ++nt) {
                    s16x8 bv = *(const s16x8*)&wv[(j + 16 * nt) * E + 8 * g + 32 * kt];
                    #pragma unroll
                    for (int sp = 0; sp < 2; ++sp)
                        #pragma unroll
                        for (int mt = 0; mt < 3; ++mt)
                            va[sp][mt][nt] = __builtin_amdgcn_mfma_f32_16x16x32_bf16(xf[sp][mt][kt], bv, va[sp][mt][nt], 0, 0, 0);
                }
            #pragma unroll
            for (int sp = 0; sp < 2; ++sp)
                #pragma unroll
                for (int mt = 0; mt < 3; ++mt)
                    #pragma unroll
                    for (int nt = 0; nt < 4; ++nt)
                        pack4(&smem[2 * S_SZ + sp * VT_SZ + (j + 16 * nt) * VP + 16 * mt + 4 * g], va[sp][mt][nt]);
        }

        // ---- pull K fragments for BOTH heads before S is overwritten by Pt ----
        s16x8 kA[2][2][3];   // [sp][h][t]
        #pragma unroll
        for (int sp = 0; sp < 2; ++sp)
            #pragma unroll
            for (int h = 0; h < 2; ++h)
                #pragma unroll
                for (int t = 0; t < 3; ++t)
                    kA[sp][h][t] = *(const s16x8*)&smem[sp * S_SZ + (j + 16 * t) * P + 32 * h + 8 * g];
        __syncthreads();

        f32x4 oa[2][2][2][3];   // [sp][h][md][nt]
        #pragma unroll
        for (int h = 0; h < 2; ++h) {
            // ---- scores: S^T = K_h @ Q_h^T ----
            f32x4 sc[2][3][3];
            #pragma unroll
            for (int sp = 0; sp < 2; ++sp)
                #pragma unroll
                for (int mt = 0; mt < 3; ++mt)
                    #pragma unroll
                    for (int nt = 0; nt < 3; ++nt)
                        sc[sp][mt][nt] = __builtin_amdgcn_mfma_f32_16x16x32_bf16(kA[sp][h][mt], qB[sp][h][nt], (f32x4)0.f, 0, 0, 0);

            // ---- softmax over keys, in-register ----
            #pragma unroll
            for (int sp = 0; sp < 2; ++sp)
                #pragma unroll
                for (int nt = 0; nt < 3; ++nt) {
                    float mx = -1e30f;
                    #pragma unroll
                    for (int mt = 0; mt < 3; ++mt)
                        #pragma unroll
                        for (int r = 0; r < 4; ++r) {
                            int key = 16 * mt + 4 * g + r;
                            float v = (key < F) ? sc[sp][mt][nt][r] * scale : -1e30f;
                            sc[sp][mt][nt][r] = v;
                            mx = fmaxf(mx, v);
                        }
                    mx = fmaxf(mx, __shfl_xor(mx, 16));
                    mx = fmaxf(mx, __shfl_xor(mx, 32));
                    float sum = 0.f;
                    #pragma unroll
                    for (int mt = 0; mt < 3; ++mt)
                        #pragma unroll
                        for (int r = 0; r < 4; ++r) {
                            float e = __expf(sc[sp][mt][nt][r] - mx);
                            sc[sp][mt][nt][r] = e;
                            sum += e;
                        }
                    sum += __shfl_xor(sum, 16);
                    sum += __shfl_xor(sum, 32);
                    float inv = 1.f / sum;
                    #pragma unroll
                    for (int mt = 0; mt < 3; ++mt)
                        #pragma unroll
                        for (int r = 0; r < 4; ++r) sc[sp][mt][nt][r] *= inv;
                }

            // ---- stage Pt (zero key-pad 48..63), read pb ----
            #pragma unroll
            for (int sp = 0; sp < 2; ++sp)
                #pragma unroll
                for (int nt = 0; nt < 3; ++nt) {
                    #pragma unroll
                    for (int mt = 0; mt < 3; ++mt)
                        pack4(&smem[sp * S_SZ + (16 * nt + j) * P + 16 * mt + 4 * g], sc[sp][mt][nt]);
                    *(ushort4*)&smem[sp * S_SZ + (16 * nt + j) * P + 48 + 4 * g] = z4;
                }
            __syncthreads();
            s16x8 pb[2][2][3];   // [sp][kt][nt]
            #pragma unroll
            for (int sp = 0; sp < 2; ++sp)
                #pragma unroll
                for (int kt = 0; kt < 2; ++kt)
                    #pragma unroll
                    for (int nt = 0; nt < 3; ++nt)
                        pb[sp][kt][nt] = *(const s16x8*)&smem[sp * S_SZ + (j + 16 * nt) * P + 8 * g + 32 * kt];
            __syncthreads();

            // ---- PV this head: out^T = V_h^T @ P_h^T ----
            #pragma unroll
            for (int sp = 0; sp < 2; ++sp)
                #pragma unroll
                for (int md = 0; md < 2; ++md)
                    #pragma unroll
                    for (int nt = 0; nt < 3; ++nt) oa[sp][h][md][nt] = (f32x4)0.f;
            #pragma unroll
            for (int kt = 0; kt < 2; ++kt)
                #pragma unroll
                for (int sp = 0; sp < 2; ++sp)
                    #pragma unroll
                    for (int md = 0; md < 2; ++md) {
                        s16x8 va = *(const s16x8*)&smem[2 * S_SZ + sp * VT_SZ + (j + 16 * (2 * h + md)) * VP + 8 * g + 32 * kt];
                        #pragma unroll
                        for (int nt = 0; nt < 3; ++nt)
                            oa[sp][h][md][nt] = __builtin_amdgcn_mfma_f32_16x16x32_bf16(va, pb[sp][kt][nt], oa[sp][h][md][nt], 0, 0, 0);
                    }
        }

        // ---- stage Ot[q][dim] (both heads) ----
        #pragma unroll
        for (int sp = 0; sp < 2; ++sp)
            #pragma unroll
            for (int h = 0; h < 2; ++h)
                #pragma unroll
                for (int md = 0; md < 2; ++md)
                    #pragma unroll
                    for (int nt = 0; nt < 3; ++nt)
                        pack4(&smem[sp * S_SZ + (16 * nt + j) * P + 32 * h + 16 * md + 4 * g], oa[sp][h][md][nt]);
        __syncthreads();

        // ---- next x^T = WO @ out^T + WR @ x^T ----
        {
            f32x4 na[2][4][3];
            #pragma unroll
            for (int sp = 0; sp < 2; ++sp)
                #pragma unroll
                for (int mt = 0; mt < 4; ++mt)
                    #pragma unroll
                    for (int nt = 0; nt < 3; ++nt) na[sp][mt][nt] = (f32x4)0.f;
            #pragma unroll
            for (int kt = 0; kt < 2; ++kt) {
                s16x8 ob[2][3];
                #pragma unroll
                for (int sp = 0; sp < 2; ++sp)
                    #pragma unroll
                    for (int nt = 0; nt < 3; ++nt)
                        ob[sp][nt] = *(const s16x8*)&smem[sp * S_SZ + (j + 16 * nt) * P + 8 * g + 32 * kt];
                #pragma unroll
                for (int mt = 0; mt < 4; ++mt) {
                    s16x8 ao = *(const s16x8*)&wo[(j + 16 * mt) * E + 8 * g + 32 * kt];
                    s16x8 ar = *(const s16x8*)&wr[(j + 16 * mt) * E + 8 * g + 32 * kt];
                    #pragma unroll
                    for (int sp = 0; sp < 2; ++sp)
                        #pragma unroll
                        for (int nt = 0; nt < 3; ++nt) {
                            na[sp][mt][nt] = __builtin_amdgcn_mfma_f32_16x16x32_bf16(ao, ob[sp][nt], na[sp][mt][nt], 0, 0, 0);
                            na[sp][mt][nt] = __builtin_amdgcn_mfma_f32_16x16x32_bf16(ar, xf[sp][nt][kt], na[sp][mt][nt], 0, 0, 0);
                        }
                }
            }
            __syncthreads();
            #pragma unroll
            for (int sp = 0; sp < 2; ++sp)
                #pragma unroll
                for (int mt = 0; mt < 4; ++mt)
                    #pragma unroll
                    for (int nt = 0; nt < 3; ++nt)
                        pack4(&smem[sp * S_SZ + (16 * nt + j) * P + 16 * mt + 4 * g], na[sp][mt][nt]);
            __syncthreads();
            #pragma unroll
            for (int sp = 0; sp < 2; ++sp)
                #pragma unroll
                for (int nt = 0; nt < 3; ++nt)
                    #pragma unroll
                    for (int kt = 0; kt < 2; ++kt)
                        xf[sp][nt][kt] = *(const s16x8*)&smem[sp * S_SZ + (j + 16 * nt) * P + 8 * g + 32 * kt];
        }
    }

    // ---------------- final linear + sigmoid (Wf loads shared) ----------------
    float accA = 0.f, accB = 0.f;
    for (int f = 0; f < F; ++f) {
        float wfv = Wf[f * E + l];
        accA += bf2f(smem[f * P + l]) * wfv;
        accB += bf2f(smem[S_SZ + f * P + l]) * wfv;
    }
    #pragma unroll
    for (int off = 32; off > 0; off >>= 1) {
        accA += __shfl_down(accA, off);
        accB += __shfl_down(accB, off);
    }
    if (l == 0) {
        out[s0] = 1.f / (1.f + __expf(-(accA + bfin[0])));
        out[s1] = 1.f / (1.f + __expf(-(accB + bfin[0])));
    }
}

extern "C" void kernel_launch(void* const* d_in, const int* in_sizes, int n_in,
                              void* d_out, int out_size, void* d_ws, size_t ws_size,
                              hipStream_t stream) {
    ushort* wsb = (ushort*)d_ws;   // 61440 ushorts = 122880 B of scratch
    cvt_weights<<<240, 256, 0, stream>>>(
        (const float*)d_in[5], (const float*)d_in[6], (const float*)d_in[7],
        (const float*)d_in[8], (const float*)d_in[9], wsb);
    autoint_mfma<<<8192, 64, 0, stream>>>(
        (const float*)d_in[0], (const int*)d_in[1],
        (const float*)d_in[2], (const float*)d_in[3],
        (const float*)d_in[4], wsb,
        (const float*)d_in[10], (const float*)d_in[11],
        (float*)d_out);
}

// Round 6
// 265.192 us; speedup vs baseline: 1.0835x; 1.0835x over previous
//
#include <hip/hip_runtime.h>
#include <hip/hip_bf16.h>
#include <math.h>

#define NN 13
#define NC 26
#define VOC 10000
#define E 64
#define LAYERS 3
#define F 39
#define P 72    // S pitch (ushorts), 144B rows
#define VP 56   // Vh pitch (ushorts), 112B rows (16B-aligned)
#define S_SZ  (48 * P)    // 3456 ushorts
#define VH_SZ (33 * VP)   // 1848 ushorts (row 32 = overrun pad)

typedef float f32x4 __attribute__((ext_vector_type(4)));
typedef short s16x8 __attribute__((ext_vector_type(8)));

__device__ __forceinline__ ushort f2bf_rne(float f) {
    uint u = __builtin_bit_cast(uint, f);
    u = (u + 0x7fffu + ((u >> 16) & 1u)) >> 16;
    return (ushort)u;
}
__device__ __forceinline__ ushort fb(float f) {   // fuses to v_cvt_pk_bf16_f32
    return __builtin_bit_cast(ushort, __float2bfloat16(f));
}
__device__ __forceinline__ float bf2f(ushort h) {
    uint u = ((uint)h) << 16;
    return __builtin_bit_cast(float, u);
}
__device__ __forceinline__ void pack4(ushort* dst, f32x4 v) {
    ushort4 p;
    p.x = fb(v[0]); p.y = fb(v[1]); p.z = fb(v[2]); p.w = fb(v[3]);
    *(ushort4*)dst = p;
}
__device__ __forceinline__ uint2 pack4r(f32x4 v) {   // 4 bf16 in 2 u32, in-register
    uint2 r;
    r.x = (uint)fb(v[0]) | ((uint)fb(v[1]) << 16);
    r.y = (uint)fb(v[2]) | ((uint)fb(v[3]) << 16);
    return r;
}

// ---- one-shot fp32 -> bf16 weight conversion into d_ws ----
// ws layout (ushort): [WQ 3*4096][WK 3*4096][WV 3*4096][WO 3*4096][WR 3*4096]
__global__ void cvt_weights(const float* __restrict__ wq, const float* __restrict__ wk,
                            const float* __restrict__ wv, const float* __restrict__ wo,
                            const float* __restrict__ wr, ushort* __restrict__ outw) {
    int i = blockIdx.x * 256 + threadIdx.x;
    if (i >= 5 * 3 * 4096) return;
    int m = i / 12288, jj = i - m * 12288;
    const float* src = (m == 0) ? wq : (m == 1) ? wk : (m == 2) ? wv : (m == 3) ? wo : wr;
    outw[i] = f2bf_rne(src[jj]);
}

__global__ __launch_bounds__(64, 4) void autoint_mfma(
    const float* __restrict__ num, const int* __restrict__ cat,
    const float* __restrict__ Wnum, const float* __restrict__ bnum,
    const float* __restrict__ tabs, const ushort* __restrict__ wsw,
    const float* __restrict__ Wf, const float* __restrict__ bfin,
    float* __restrict__ out)
{
    __shared__ __align__(16) ushort smem[S_SZ + VH_SZ];   // 10608 B
    ushort* S  = smem;          // [48][72] staging: x / Q / K / Pt / Ot / x'
    ushort* Vh = smem + S_SZ;   // [33][56] per-head half-V [dim-in-head][key]

    const int l = threadIdx.x;
    const int j = l & 15;
    const int g = l >> 4;
    const int s = blockIdx.x;

    ushort4 z4; z4.x = z4.y = z4.z = z4.w = 0;

    // one-time zeros: Vh key-cols 48..55 (rows 0..31) + overrun pad row 32 cols 0..7.
    // Staging only ever writes cols 0..47 of rows 0..31, so these stay zero.
    {
        int r = l & 31, cs = 48 + 4 * (l >> 5);
        *(ushort4*)&Vh[r * VP + cs] = z4;
        if (l < 2) *(ushort4*)&Vh[32 * VP + 4 * l] = z4;
    }

    // ---------------- embedding into S ----------------
    for (int f = 0; f < NN; ++f) {
        float v = num[s * NN + f];
        S[f * P + l] = fb(v * Wnum[f * E + l] + bnum[f * E + l]);
    }
    for (int c = 0; c < NC; ++c) {
        int idx = cat[s * NC + c];
        S[(NN + c) * P + l] = fb(tabs[((size_t)(c * VOC + idx)) * E + l]);
    }
    #pragma unroll
    for (int r = F; r < 48; ++r) S[r * P + l] = 0;
    __syncthreads();

    // x fragments in registers: row j+16nt, dims 8g..8g+7 (+32kt)
    s16x8 xf[3][2];
    #pragma unroll
    for (int nt = 0; nt < 3; ++nt)
        #pragma unroll
        for (int kt = 0; kt < 2; ++kt)
            xf[nt][kt] = *(const s16x8*)&S[(j + 16 * nt) * P + 8 * g + 32 * kt];

    const float scale = 0.17677669529663687f; // 1/sqrt(32)

    for (int l3 = 0; l3 < LAYERS; ++l3) {
        const ushort* wq = wsw + 0 * 12288 + l3 * 4096;
        const ushort* wk = wsw + 1 * 12288 + l3 * 4096;
        const ushort* wv = wsw + 2 * 12288 + l3 * 4096;
        const ushort* wo = wsw + 3 * 12288 + l3 * 4096;
        const ushort* wr = wsw + 4 * 12288 + l3 * 4096;

        // ---- Q^T = WQ @ x^T -> stage in S -> qB frags (both heads) ----
        s16x8 qB[2][3];
        {
            f32x4 qa[4][3];
            #pragma unroll
            for (int mt = 0; mt < 4; ++mt)
                #pragma unroll
                for (int nt = 0; nt < 3; ++nt) qa[mt][nt] = (f32x4)0.f;
            #pragma unroll
            for (int kt = 0; kt < 2; ++kt)
                #pragma unroll
                for (int mt = 0; mt < 4; ++mt) {
                    s16x8 aq = *(const s16x8*)&wq[(j + 16 * mt) * E + 8 * g + 32 * kt];
                    #pragma unroll
                    for (int nt = 0; nt < 3; ++nt)
                        qa[mt][nt] = __builtin_amdgcn_mfma_f32_16x16x32_bf16(aq, xf[nt][kt], qa[mt][nt], 0, 0, 0);
                }
            __syncthreads();   // xf LDS reads complete before overwrite
            #pragma unroll
            for (int mt = 0; mt < 4; ++mt)
                #pragma unroll
                for (int nt = 0; nt < 3; ++nt)
                    pack4(&S[(j + 16 * nt) * P + 16 * mt + 4 * g], qa[mt][nt]);  // Q[field][dim]
            __syncthreads();
            #pragma unroll
            for (int h = 0; h < 2; ++h)
                #pragma unroll
                for (int t = 0; t < 3; ++t)
                    qB[h][t] = *(const s16x8*)&S[(j + 16 * t) * P + 32 * h + 8 * g];
            __syncthreads();
        }

        // ---- K^T = WK @ x^T -> stage in S ----
        {
            f32x4 ka[4][3];
            #pragma unroll
            for (int mt = 0; mt < 4; ++mt)
                #pragma unroll
                for (int nt = 0; nt < 3; ++nt) ka[mt][nt] = (f32x4)0.f;
            #pragma unroll
            for (int kt = 0; kt < 2; ++kt)
                #pragma unroll
                for (int mt = 0; mt < 4; ++mt) {
                    s16x8 ak = *(const s16x8*)&wk[(j + 16 * mt) * E + 8 * g + 32 * kt];
                    #pragma unroll
                    for (int nt = 0; nt < 3; ++nt)
                        ka[mt][nt] = __builtin_amdgcn_mfma_f32_16x16x32_bf16(ak, xf[nt][kt], ka[mt][nt], 0, 0, 0);
                }
            #pragma unroll
            for (int mt = 0; mt < 4; ++mt)
                #pragma unroll
                for (int nt = 0; nt < 3; ++nt)
                    pack4(&S[(j + 16 * nt) * P + 16 * mt + 4 * g], ka[mt][nt]);  // K[field][dim]
            __syncthreads();
        }

        // ---- V = x @ WV^T -> pack to registers (vp[mt][nt] = 4 bf16 along field) ----
        uint2 vp[3][4];
        {
            f32x4 va[3][4];
            #pragma unroll
            for (int mt = 0; mt < 3; ++mt)
                #pragma unroll
                for (int nt = 0; nt < 4; ++nt) va[mt][nt] = (f32x4)0.f;
            #pragma unroll
            for (int kt = 0; kt < 2; ++kt)
                #pragma unroll
                for (int nt = 0; nt < 4; ++nt) {
                    s16x8 bv = *(const s16x8*)&wv[(j + 16 * nt) * E + 8 * g + 32 * kt];
                    #pragma unroll
                    for (int mt = 0; mt < 3; ++mt)
                        va[mt][nt] = __builtin_amdgcn_mfma_f32_16x16x32_bf16(xf[mt][kt], bv, va[mt][nt], 0, 0, 0);
                }
            #pragma unroll
            for (int mt = 0; mt < 3; ++mt)
                #pragma unroll
                for (int nt = 0; nt < 4; ++nt)
                    vp[mt][nt] = pack4r(va[mt][nt]);   // V[field=16mt+4g+r][dim=16nt+j]
        }

        // ---- K fragments for BOTH heads (before S is overwritten by Pt) ----
        s16x8 kA[2][3];
        #pragma unroll
        for (int h = 0; h < 2; ++h)
            #pragma unroll
            for (int t = 0; t < 3; ++t)
                kA[h][t] = *(const s16x8*)&S[(j + 16 * t) * P + 32 * h + 8 * g];
        __syncthreads();

        f32x4 oa[2][2][3];   // [h][md][nt]
        #pragma unroll
        for (int h = 0; h < 2; ++h) {
            // ---- scores: S^T = K_h @ Q_h^T ----
            f32x4 sc[3][3];
            #pragma unroll
            for (int mt = 0; mt < 3; ++mt)
                #pragma unroll
                for (int nt = 0; nt < 3; ++nt)
                    sc[mt][nt] = __builtin_amdgcn_mfma_f32_16x16x32_bf16(kA[h][mt], qB[h][nt], (f32x4)0.f, 0, 0, 0);

            // ---- softmax over keys, in-register ----
            #pragma unroll
            for (int nt = 0; nt < 3; ++nt) {
                float mx = -1e30f;
                #pragma unroll
                for (int mt = 0; mt < 3; ++mt)
                    #pragma unroll
                    for (int r = 0; r < 4; ++r) {
                        int key = 16 * mt + 4 * g + r;
                        float v = (key < F) ? sc[mt][nt][r] * scale : -1e30f;
                        sc[mt][nt][r] = v;
                        mx = fmaxf(mx, v);
                    }
                mx = fmaxf(mx, __shfl_xor(mx, 16));
                mx = fmaxf(mx, __shfl_xor(mx, 32));
                float sum = 0.f;
                #pragma unroll
                for (int mt = 0; mt < 3; ++mt)
                    #pragma unroll
                    for (int r = 0; r < 4; ++r) {
                        float e = __expf(sc[mt][nt][r] - mx);
                        sc[mt][nt][r] = e;
                        sum += e;
                    }
                sum += __shfl_xor(sum, 16);
                sum += __shfl_xor(sum, 32);
                float inv = 1.f / sum;
                #pragma unroll
                for (int mt = 0; mt < 3; ++mt)
                    #pragma unroll
                    for (int r = 0; r < 4; ++r) sc[mt][nt][r] *= inv;
            }

            // ---- stage Pt (zero key-pad 48..63) + this head's half-V ----
            #pragma unroll
            for (int nt = 0; nt < 3; ++nt) {
                #pragma unroll
                for (int mt = 0; mt < 3; ++mt)
                    pack4(&S[(16 * nt + j) * P + 16 * mt + 4 * g], sc[mt][nt]);
                *(ushort4*)&S[(16 * nt + j) * P + 48 + 4 * g] = z4;
            }
            #pragma unroll
            for (int md = 0; md < 2; ++md)
                #pragma unroll
                for (int mt = 0; mt < 3; ++mt)
                    *(uint2*)&Vh[(j + 16 * md) * VP + 16 * mt + 4 * g] = vp[mt][2 * h + md];
            __syncthreads();

            // ---- pb read, PV: out^T = V_h^T @ P_h^T ----
            s16x8 pb[2][3];
            #pragma unroll
            for (int kt = 0; kt < 2; ++kt)
                #pragma unroll
                for (int nt = 0; nt < 3; ++nt)
                    pb[kt][nt] = *(const s16x8*)&S[(j + 16 * nt) * P + 8 * g + 32 * kt];
            #pragma unroll
            for (int md = 0; md < 2; ++md)
                #pragma unroll
                for (int nt = 0; nt < 3; ++nt) oa[h][md][nt] = (f32x4)0.f;
            #pragma unroll
            for (int kt = 0; kt < 2; ++kt)
                #pragma unroll
                for (int md = 0; md < 2; ++md) {
                    s16x8 va = *(const s16x8*)&Vh[(j + 16 * md) * VP + 8 * g + 32 * kt];
                    #pragma unroll
                    for (int nt = 0; nt < 3; ++nt)
                        oa[h][md][nt] = __builtin_amdgcn_mfma_f32_16x16x32_bf16(va, pb[kt][nt], oa[h][md][nt], 0, 0, 0);
                }
            __syncthreads();   // S + Vh reads done before next h overwrites
        }

        // ---- stage Ot[q][dim] (both heads) ----
        #pragma unroll
        for (int h = 0; h < 2; ++h)
            #pragma unroll
            for (int md = 0; md < 2; ++md)
                #pragma unroll
                for (int nt = 0; nt < 3; ++nt)
                    pack4(&S[(16 * nt + j) * P + 32 * h + 16 * md + 4 * g], oa[h][md][nt]);
        __syncthreads();

        // ---- next x^T = WO @ out^T + WR @ x^T ----
        {
            f32x4 na[4][3];
            #pragma unroll
            for (int mt = 0; mt < 4; ++mt)
                #pragma unroll
                for (int nt = 0; nt < 3; ++nt) na[mt][nt] = (f32x4)0.f;
            #pragma unroll
            for (int kt = 0; kt < 2; ++kt) {
                s16x8 ob[3];
                #pragma unroll
                for (int nt = 0; nt < 3; ++nt)
                    ob[nt] = *(const s16x8*)&S[(j + 16 * nt) * P + 8 * g + 32 * kt];
                #pragma unroll
                for (int mt = 0; mt < 4; ++mt) {
                    s16x8 ao = *(const s16x8*)&wo[(j + 16 * mt) * E + 8 * g + 32 * kt];
                    s16x8 ar = *(const s16x8*)&wr[(j + 16 * mt) * E + 8 * g + 32 * kt];
                    #pragma unroll
                    for (int nt = 0; nt < 3; ++nt) {
                        na[mt][nt] = __builtin_amdgcn_mfma_f32_16x16x32_bf16(ao, ob[nt], na[mt][nt], 0, 0, 0);
                        na[mt][nt] = __builtin_amdgcn_mfma_f32_16x16x32_bf16(ar, xf[nt][kt], na[mt][nt], 0, 0, 0);
                    }
                }
            }
            __syncthreads();
            #pragma unroll
            for (int mt = 0; mt < 4; ++mt)
                #pragma unroll
                for (int nt = 0; nt < 3; ++nt)
                    pack4(&S[(16 * nt + j) * P + 16 * mt + 4 * g], na[mt][nt]);  // x'[field][dim]
            __syncthreads();
            #pragma unroll
            for (int nt = 0; nt < 3; ++nt)
                #pragma unroll
                for (int kt = 0; kt < 2; ++kt)
                    xf[nt][kt] = *(const s16x8*)&S[(j + 16 * nt) * P + 8 * g + 32 * kt];
        }
    }

    // ---------------- final linear + sigmoid ----------------
    float acc = 0.f;
    for (int f = 0; f < F; ++f)
        acc += bf2f(S[f * P + l]) * Wf[f * E + l];
    #pragma unroll
    for (int off = 32; off > 0; off >>= 1) acc += __shfl_down(acc, off);
    if (l == 0) out[s] = 1.f / (1.f + __expf(-(acc + bfin[0])));
}

extern "C" void kernel_launch(void* const* d_in, const int* in_sizes, int n_in,
                              void* d_out, int out_size, void* d_ws, size_t ws_size,
                              hipStream_t stream) {
    ushort* wsb = (ushort*)d_ws;   // 61440 ushorts = 122880 B of scratch
    cvt_weights<<<240, 256, 0, stream>>>(
        (const float*)d_in[5], (const float*)d_in[6], (const float*)d_in[7],
        (const float*)d_in[8], (const float*)d_in[9], wsb);
    autoint_mfma<<<16384, 64, 0, stream>>>(
        (const float*)d_in[0], (const int*)d_in[1],
        (const float*)d_in[2], (const float*)d_in[3],
        (const float*)d_in[4], wsb,
        (const float*)d_in[10], (const float*)d_in[11],
        (float*)d_out);
}

// Round 7
// 244.450 us; speedup vs baseline: 1.1754x; 1.0849x over previous
//
#include <hip/hip_runtime.h>
#include <hip/hip_bf16.h>
#include <math.h>

#define NN 13
#define NC 26
#define VOC 10000
#define E 64
#define LAYERS 3
#define F 39
#define P 72    // S pitch (ushorts), 144B rows
#define VP 56   // Vh pitch (ushorts), 112B rows (16B-aligned)
#define S_SZ  (48 * P)    // 3456 ushorts
#define VH_SZ (33 * VP)   // 1848 ushorts (row 32 = overrun pad)

typedef float f32x4 __attribute__((ext_vector_type(4)));
typedef short s16x8 __attribute__((ext_vector_type(8)));

__device__ __forceinline__ ushort f2bf_rne(float f) {
    uint u = __builtin_bit_cast(uint, f);
    u = (u + 0x7fffu + ((u >> 16) & 1u)) >> 16;
    return (ushort)u;
}
__device__ __forceinline__ ushort fb(float f) {   // fuses to v_cvt_pk_bf16_f32
    return __builtin_bit_cast(ushort, __float2bfloat16(f));
}
__device__ __forceinline__ float bf2f(ushort h) {
    uint u = ((uint)h) << 16;
    return __builtin_bit_cast(float, u);
}
__device__ __forceinline__ void pack4(ushort* dst, f32x4 v) {
    ushort4 p;
    p.x = fb(v[0]); p.y = fb(v[1]); p.z = fb(v[2]); p.w = fb(v[3]);
    *(ushort4*)dst = p;
}

// ---- one-shot fp32 -> bf16 weight conversion into d_ws ----
// ws layout (ushort): [WQ 3*4096][WK 3*4096][WV 3*4096][WO 3*4096][WR 3*4096]
__global__ void cvt_weights(const float* __restrict__ wq, const float* __restrict__ wk,
                            const float* __restrict__ wv, const float* __restrict__ wo,
                            const float* __restrict__ wr, ushort* __restrict__ outw) {
    int i = blockIdx.x * 256 + threadIdx.x;
    if (i >= 5 * 3 * 4096) return;
    int m = i / 12288, jj = i - m * 12288;
    const float* src = (m == 0) ? wq : (m == 1) ? wk : (m == 2) ? wv : (m == 3) ? wo : wr;
    outw[i] = f2bf_rne(src[jj]);
}

__global__ __launch_bounds__(64, 3) void autoint_mfma(
    const float* __restrict__ num, const int* __restrict__ cat,
    const float* __restrict__ Wnum, const float* __restrict__ bnum,
    const float* __restrict__ tabs, const ushort* __restrict__ wsw,
    const float* __restrict__ Wf, const float* __restrict__ bfin,
    float* __restrict__ out)
{
    __shared__ __align__(16) ushort smem[S_SZ + VH_SZ];   // 10608 B
    ushort* S  = smem;          // [48][72] staging: x / Q / K / Pt / Ot / x'
    ushort* Vh = smem + S_SZ;   // [33][56] per-head half-V [dim-in-head][key]

    const int l = threadIdx.x;
    const int j = l & 15;
    const int g = l >> 4;
    const int s = blockIdx.x;

    ushort4 z4; z4.x = z4.y = z4.z = z4.w = 0;

    // one-time zeros: Vh key-cols 48..55 (rows 0..31) + overrun pad row 32 cols 0..7.
    // Staging only ever writes cols 0..47 of rows 0..31, so these stay zero.
    {
        int r = l & 31, cs = 48 + 4 * (l >> 5);
        *(ushort4*)&Vh[r * VP + cs] = z4;
        if (l < 2) *(ushort4*)&Vh[32 * VP + 4 * l] = z4;
    }

    // ---------------- embedding into S ----------------
    for (int f = 0; f < NN; ++f) {
        float v = num[s * NN + f];
        S[f * P + l] = fb(v * Wnum[f * E + l] + bnum[f * E + l]);
    }
    for (int c = 0; c < NC; ++c) {
        int idx = cat[s * NC + c];
        S[(NN + c) * P + l] = fb(tabs[((size_t)(c * VOC + idx)) * E + l]);
    }
    #pragma unroll
    for (int r = F; r < 48; ++r) S[r * P + l] = 0;
    __syncthreads();

    // x fragments in registers: row j+16nt, dims 8g..8g+7 (+32kt)
    s16x8 xf[3][2];
    #pragma unroll
    for (int nt = 0; nt < 3; ++nt)
        #pragma unroll
        for (int kt = 0; kt < 2; ++kt)
            xf[nt][kt] = *(const s16x8*)&S[(j + 16 * nt) * P + 8 * g + 32 * kt];

    const float scale = 0.17677669529663687f; // 1/sqrt(32)

    for (int l3 = 0; l3 < LAYERS; ++l3) {
        const ushort* wq = wsw + 0 * 12288 + l3 * 4096;
        const ushort* wk = wsw + 1 * 12288 + l3 * 4096;
        const ushort* wv = wsw + 2 * 12288 + l3 * 4096;
        const ushort* wo = wsw + 3 * 12288 + l3 * 4096;
        const ushort* wr = wsw + 4 * 12288 + l3 * 4096;

        // ---- Q^T = WQ @ x^T -> stage in S -> qB frags (both heads) ----
        s16x8 qB[2][3];
        {
            f32x4 qa[4][3];
            #pragma unroll
            for (int mt = 0; mt < 4; ++mt)
                #pragma unroll
                for (int nt = 0; nt < 3; ++nt) qa[mt][nt] = (f32x4)0.f;
            #pragma unroll
            for (int kt = 0; kt < 2; ++kt)
                #pragma unroll
                for (int mt = 0; mt < 4; ++mt) {
                    s16x8 aq = *(const s16x8*)&wq[(j + 16 * mt) * E + 8 * g + 32 * kt];
                    #pragma unroll
                    for (int nt = 0; nt < 3; ++nt)
                        qa[mt][nt] = __builtin_amdgcn_mfma_f32_16x16x32_bf16(aq, xf[nt][kt], qa[mt][nt], 0, 0, 0);
                }
            __syncthreads();   // xf LDS reads complete before overwrite
            #pragma unroll
            for (int mt = 0; mt < 4; ++mt)
                #pragma unroll
                for (int nt = 0; nt < 3; ++nt)
                    pack4(&S[(j + 16 * nt) * P + 16 * mt + 4 * g], qa[mt][nt]);  // Q[field][dim]
            __syncthreads();
            #pragma unroll
            for (int h = 0; h < 2; ++h)
                #pragma unroll
                for (int t = 0; t < 3; ++t)
                    qB[h][t] = *(const s16x8*)&S[(j + 16 * t) * P + 32 * h + 8 * g];
            __syncthreads();
        }

        // ---- K^T = WK @ x^T -> stage in S ----
        {
            f32x4 ka[4][3];
            #pragma unroll
            for (int mt = 0; mt < 4; ++mt)
                #pragma unroll
                for (int nt = 0; nt < 3; ++nt) ka[mt][nt] = (f32x4)0.f;
            #pragma unroll
            for (int kt = 0; kt < 2; ++kt)
                #pragma unroll
                for (int mt = 0; mt < 4; ++mt) {
                    s16x8 ak = *(const s16x8*)&wk[(j + 16 * mt) * E + 8 * g + 32 * kt];
                    #pragma unroll
                    for (int nt = 0; nt < 3; ++nt)
                        ka[mt][nt] = __builtin_amdgcn_mfma_f32_16x16x32_bf16(ak, xf[nt][kt], ka[mt][nt], 0, 0, 0);
                }
            #pragma unroll
            for (int mt = 0; mt < 4; ++mt)
                #pragma unroll
                for (int nt = 0; nt < 3; ++nt)
                    pack4(&S[(j + 16 * nt) * P + 16 * mt + 4 * g], ka[mt][nt]);  // K[field][dim]
            __syncthreads();
        }

        // ---- K fragments for BOTH heads (before S is overwritten by Pt) ----
        s16x8 kA[2][3];
        #pragma unroll
        for (int h = 0; h < 2; ++h)
            #pragma unroll
            for (int t = 0; t < 3; ++t)
                kA[h][t] = *(const s16x8*)&S[(j + 16 * t) * P + 32 * h + 8 * g];
        __syncthreads();

        f32x4 oa[2][2][3];   // [h][md][nt]
        #pragma unroll
        for (int h = 0; h < 2; ++h) {
            // ---- scores: S^T = K_h @ Q_h^T ----
            f32x4 sc[3][3];
            #pragma unroll
            for (int mt = 0; mt < 3; ++mt)
                #pragma unroll
                for (int nt = 0; nt < 3; ++nt)
                    sc[mt][nt] = __builtin_amdgcn_mfma_f32_16x16x32_bf16(kA[h][mt], qB[h][nt], (f32x4)0.f, 0, 0, 0);

            // ---- this head's half-V: V = x @ WV^T, dims 32h..32h+31 (independent of softmax -> overlaps) ----
            f32x4 va[3][2];
            #pragma unroll
            for (int mt = 0; mt < 3; ++mt)
                #pragma unroll
                for (int md = 0; md < 2; ++md) va[mt][md] = (f32x4)0.f;
            #pragma unroll
            for (int kt = 0; kt < 2; ++kt)
                #pragma unroll
                for (int md = 0; md < 2; ++md) {
                    s16x8 bv = *(const s16x8*)&wv[(j + 16 * (2 * h + md)) * E + 8 * g + 32 * kt];
                    #pragma unroll
                    for (int mt = 0; mt < 3; ++mt)
                        va[mt][md] = __builtin_amdgcn_mfma_f32_16x16x32_bf16(xf[mt][kt], bv, va[mt][md], 0, 0, 0);
                }

            // ---- softmax over keys, in-register ----
            #pragma unroll
            for (int nt = 0; nt < 3; ++nt) {
                float mx = -1e30f;
                #pragma unroll
                for (int mt = 0; mt < 3; ++mt)
                    #pragma unroll
                    for (int r = 0; r < 4; ++r) {
                        int key = 16 * mt + 4 * g + r;
                        float v = (key < F) ? sc[mt][nt][r] * scale : -1e30f;
                        sc[mt][nt][r] = v;
                        mx = fmaxf(mx, v);
                    }
                mx = fmaxf(mx, __shfl_xor(mx, 16));
                mx = fmaxf(mx, __shfl_xor(mx, 32));
                float sum = 0.f;
                #pragma unroll
                for (int mt = 0; mt < 3; ++mt)
                    #pragma unroll
                    for (int r = 0; r < 4; ++r) {
                        float e = __expf(sc[mt][nt][r] - mx);
                        sc[mt][nt][r] = e;
                        sum += e;
                    }
                sum += __shfl_xor(sum, 16);
                sum += __shfl_xor(sum, 32);
                float inv = 1.f / sum;
                #pragma unroll
                for (int mt = 0; mt < 3; ++mt)
                    #pragma unroll
                    for (int r = 0; r < 4; ++r) sc[mt][nt][r] *= inv;
            }

            // ---- stage Pt (zero key-pad 48..63) + this head's half-V ----
            #pragma unroll
            for (int nt = 0; nt < 3; ++nt) {
                #pragma unroll
                for (int mt = 0; mt < 3; ++mt)
                    pack4(&S[(16 * nt + j) * P + 16 * mt + 4 * g], sc[mt][nt]);
                *(ushort4*)&S[(16 * nt + j) * P + 48 + 4 * g] = z4;
            }
            #pragma unroll
            for (int md = 0; md < 2; ++md)
                #pragma unroll
                for (int mt = 0; mt < 3; ++mt)
                    pack4(&Vh[(j + 16 * md) * VP + 16 * mt + 4 * g], va[mt][md]);  // Vh[dim-in-head][key]
            __syncthreads();

            // ---- pb read, PV: out^T = V_h^T @ P_h^T ----
            s16x8 pb[2][3];
            #pragma unroll
            for (int kt = 0; kt < 2; ++kt)
                #pragma unroll
                for (int nt = 0; nt < 3; ++nt)
                    pb[kt][nt] = *(const s16x8*)&S[(j + 16 * nt) * P + 8 * g + 32 * kt];
            #pragma unroll
            for (int md = 0; md < 2; ++md)
                #pragma unroll
                for (int nt = 0; nt < 3; ++nt) oa[h][md][nt] = (f32x4)0.f;
            #pragma unroll
            for (int kt = 0; kt < 2; ++kt)
                #pragma unroll
                for (int md = 0; md < 2; ++md) {
                    s16x8 va2 = *(const s16x8*)&Vh[(j + 16 * md) * VP + 8 * g + 32 * kt];
                    #pragma unroll
                    for (int nt = 0; nt < 3; ++nt)
                        oa[h][md][nt] = __builtin_amdgcn_mfma_f32_16x16x32_bf16(va2, pb[kt][nt], oa[h][md][nt], 0, 0, 0);
                }
            __syncthreads();   // S + Vh reads done before next h overwrites
        }

        // ---- stage Ot[q][dim] (both heads) ----
        #pragma unroll
        for (int h = 0; h < 2; ++h)
            #pragma unroll
            for (int md = 0; md < 2; ++md)
                #pragma unroll
                for (int nt = 0; nt < 3; ++nt)
                    pack4(&S[(16 * nt + j) * P + 32 * h + 16 * md + 4 * g], oa[h][md][nt]);
        __syncthreads();

        // ---- next x^T = WO @ out^T + WR @ x^T ----
        {
            f32x4 na[4][3];
            #pragma unroll
            for (int mt = 0; mt < 4; ++mt)
                #pragma unroll
                for (int nt = 0; nt < 3; ++nt) na[mt][nt] = (f32x4)0.f;
            #pragma unroll
            for (int kt = 0; kt < 2; ++kt) {
                s16x8 ob[3];
                #pragma unroll
                for (int nt = 0; nt < 3; ++nt)
                    ob[nt] = *(const s16x8*)&S[(j + 16 * nt) * P + 8 * g + 32 * kt];
                #pragma unroll
                for (int mt = 0; mt < 4; ++mt) {
                    s16x8 ao = *(const s16x8*)&wo[(j + 16 * mt) * E + 8 * g + 32 * kt];
                    s16x8 ar = *(const s16x8*)&wr[(j + 16 * mt) * E + 8 * g + 32 * kt];
                    #pragma unroll
                    for (int nt = 0; nt < 3; ++nt) {
                        na[mt][nt] = __builtin_amdgcn_mfma_f32_16x16x32_bf16(ao, ob[nt], na[mt][nt], 0, 0, 0);
                        na[mt][nt] = __builtin_amdgcn_mfma_f32_16x16x32_bf16(ar, xf[nt][kt], na[mt][nt], 0, 0, 0);
                    }
                }
            }
            __syncthreads();
            #pragma unroll
            for (int mt = 0; mt < 4; ++mt)
                #pragma unroll
                for (int nt = 0; nt < 3; ++nt)
                    pack4(&S[(16 * nt + j) * P + 16 * mt + 4 * g], na[mt][nt]);  // x'[field][dim]
            __syncthreads();
            #pragma unroll
            for (int nt = 0; nt < 3; ++nt)
                #pragma unroll
                for (int kt = 0; kt < 2; ++kt)
                    xf[nt][kt] = *(const s16x8*)&S[(j + 16 * nt) * P + 8 * g + 32 * kt];
        }
    }

    // ---------------- final linear + sigmoid ----------------
    float acc = 0.f;
    for (int f = 0; f < F; ++f)
        acc += bf2f(S[f * P + l]) * Wf[f * E + l];
    #pragma unroll
    for (int off = 32; off > 0; off >>= 1) acc += __shfl_down(acc, off);
    if (l == 0) out[s] = 1.f / (1.f + __expf(-(acc + bfin[0])));
}

extern "C" void kernel_launch(void* const* d_in, const int* in_sizes, int n_in,
                              void* d_out, int out_size, void* d_ws, size_t ws_size,
                              hipStream_t stream) {
    ushort* wsb = (ushort*)d_ws;   // 61440 ushorts = 122880 B of scratch
    cvt_weights<<<240, 256, 0, stream>>>(
        (const float*)d_in[5], (const float*)d_in[6], (const float*)d_in[7],
        (const float*)d_in[8], (const float*)d_in[9], wsb);
    autoint_mfma<<<16384, 64, 0, stream>>>(
        (const float*)d_in[0], (const int*)d_in[1],
        (const float*)d_in[2], (const float*)d_in[3],
        (const float*)d_in[4], wsb,
        (const float*)d_in[10], (const float*)d_in[11],
        (float*)d_out);
}

// Round 8
// 242.987 us; speedup vs baseline: 1.1825x; 1.0060x over previous
//
#include <hip/hip_runtime.h>
#include <hip/hip_bf16.h>
#include <math.h>

#define NN 13
#define NC 26
#define VOC 10000
#define E 64
#define LAYERS 3
#define F 39
#define P 72    // S pitch (ushorts), 144B rows
#define VP 56   // Vh pitch (ushorts), 112B rows (16B-aligned)
#define S_SZ  (48 * P)    // 3456 ushorts
#define VH_SZ (33 * VP)   // 1848 ushorts (row 32 = overrun pad)

typedef float f32x4 __attribute__((ext_vector_type(4)));
typedef short s16x8 __attribute__((ext_vector_type(8)));

__device__ __forceinline__ ushort f2bf_rne(float f) {
    uint u = __builtin_bit_cast(uint, f);
    u = (u + 0x7fffu + ((u >> 16) & 1u)) >> 16;
    return (ushort)u;
}
__device__ __forceinline__ ushort fb(float f) {   // fuses to v_cvt_pk_bf16_f32
    return __builtin_bit_cast(ushort, __float2bfloat16(f));
}
__device__ __forceinline__ float bf2f(ushort h) {
    uint u = ((uint)h) << 16;
    return __builtin_bit_cast(float, u);
}
__device__ __forceinline__ void pack4(ushort* dst, f32x4 v) {
    ushort4 p;
    p.x = fb(v[0]); p.y = fb(v[1]); p.z = fb(v[2]); p.w = fb(v[3]);
    *(ushort4*)dst = p;
}

// ---- one-shot fp32 -> bf16 weight conversion into d_ws ----
// ws layout (ushort): [WQ 3*4096][WK 3*4096][WV 3*4096][WO 3*4096][WR 3*4096]
__global__ void cvt_weights(const float* __restrict__ wq, const float* __restrict__ wk,
                            const float* __restrict__ wv, const float* __restrict__ wo,
                            const float* __restrict__ wr, ushort* __restrict__ outw) {
    int i = blockIdx.x * 256 + threadIdx.x;
    if (i >= 5 * 3 * 4096) return;
    int m = i / 12288, jj = i - m * 12288;
    const float* src = (m == 0) ? wq : (m == 1) ? wk : (m == 2) ? wv : (m == 3) ? wo : wr;
    outw[i] = f2bf_rne(src[jj]);
}

__global__ __launch_bounds__(64, 3) void autoint_mfma(
    const float* __restrict__ num, const int* __restrict__ cat,
    const float* __restrict__ Wnum, const float* __restrict__ bnum,
    const float* __restrict__ tabs, const ushort* __restrict__ wsw,
    const float* __restrict__ Wf, const float* __restrict__ bfin,
    float* __restrict__ out)
{
    __shared__ __align__(16) ushort smem[S_SZ + VH_SZ];   // 10608 B
    ushort* S  = smem;          // [48][72] staging: x / Q / K / Pt / Ot / x'
    ushort* Vh = smem + S_SZ;   // [33][56] per-head half-V [dim-in-head][key]

    const int l = threadIdx.x;
    const int j = l & 15;
    const int g = l >> 4;
    const int s = blockIdx.x;

    ushort4 z4; z4.x = z4.y = z4.z = z4.w = 0;

    // one-time zeros: Vh key-cols 48..55 (rows 0..31) + overrun pad row 32 cols 0..7.
    {
        int r = l & 31, cs = 48 + 4 * (l >> 5);
        *(ushort4*)&Vh[r * VP + cs] = z4;
        if (l < 2) *(ushort4*)&Vh[32 * VP + 4 * l] = z4;
    }

    // ---------------- embedding into S ----------------
    for (int f = 0; f < NN; ++f) {
        float v = num[s * NN + f];
        S[f * P + l] = fb(v * Wnum[f * E + l] + bnum[f * E + l]);
    }
    for (int c = 0; c < NC; ++c) {
        int idx = cat[s * NC + c];
        S[(NN + c) * P + l] = fb(tabs[((size_t)(c * VOC + idx)) * E + l]);
    }
    #pragma unroll
    for (int r = F; r < 48; ++r) S[r * P + l] = 0;
    __syncthreads();

    // x fragments in registers: row j+16nt, dims 8g..8g+7 (+32kt)
    s16x8 xf[3][2];
    #pragma unroll
    for (int nt = 0; nt < 3; ++nt)
        #pragma unroll
        for (int kt = 0; kt < 2; ++kt)
            xf[nt][kt] = *(const s16x8*)&S[(j + 16 * nt) * P + 8 * g + 32 * kt];

    const float scale = 0.17677669529663687f; // 1/sqrt(32)

    for (int l3 = 0; l3 < LAYERS; ++l3) {
        const ushort* wq = wsw + 0 * 12288 + l3 * 4096;
        const ushort* wk = wsw + 1 * 12288 + l3 * 4096;
        const ushort* wv = wsw + 2 * 12288 + l3 * 4096;
        const ushort* wo = wsw + 3 * 12288 + l3 * 4096;
        const ushort* wr = wsw + 4 * 12288 + l3 * 4096;

        // ---- Q^T = WQ @ x^T : batch-issue all 8 weight frags, then MFMA ----
        s16x8 qB[2][3];
        {
            s16x8 wqf[2][4];
            #pragma unroll
            for (int kt = 0; kt < 2; ++kt)
                #pragma unroll
                for (int mt = 0; mt < 4; ++mt)
                    wqf[kt][mt] = *(const s16x8*)&wq[(j + 16 * mt) * E + 8 * g + 32 * kt];
            f32x4 qa[4][3];
            #pragma unroll
            for (int mt = 0; mt < 4; ++mt)
                #pragma unroll
                for (int nt = 0; nt < 3; ++nt) qa[mt][nt] = (f32x4)0.f;
            #pragma unroll
            for (int kt = 0; kt < 2; ++kt)
                #pragma unroll
                for (int mt = 0; mt < 4; ++mt)
                    #pragma unroll
                    for (int nt = 0; nt < 3; ++nt)
                        qa[mt][nt] = __builtin_amdgcn_mfma_f32_16x16x32_bf16(wqf[kt][mt], xf[nt][kt], qa[mt][nt], 0, 0, 0);
            __syncthreads();   // xf LDS reads complete before overwrite
            #pragma unroll
            for (int mt = 0; mt < 4; ++mt)
                #pragma unroll
                for (int nt = 0; nt < 3; ++nt)
                    pack4(&S[(j + 16 * nt) * P + 16 * mt + 4 * g], qa[mt][nt]);  // Q[field][dim]
            __syncthreads();
            #pragma unroll
            for (int h = 0; h < 2; ++h)
                #pragma unroll
                for (int t = 0; t < 3; ++t)
                    qB[h][t] = *(const s16x8*)&S[(j + 16 * t) * P + 32 * h + 8 * g];
            __syncthreads();
        }

        // ---- K^T = WK @ x^T ----
        {
            s16x8 wkf[2][4];
            #pragma unroll
            for (int kt = 0; kt < 2; ++kt)
                #pragma unroll
                for (int mt = 0; mt < 4; ++mt)
                    wkf[kt][mt] = *(const s16x8*)&wk[(j + 16 * mt) * E + 8 * g + 32 * kt];
            f32x4 ka[4][3];
            #pragma unroll
            for (int mt = 0; mt < 4; ++mt)
                #pragma unroll
                for (int nt = 0; nt < 3; ++nt) ka[mt][nt] = (f32x4)0.f;
            #pragma unroll
            for (int kt = 0; kt < 2; ++kt)
                #pragma unroll
                for (int mt = 0; mt < 4; ++mt)
                    #pragma unroll
                    for (int nt = 0; nt < 3; ++nt)
                        ka[mt][nt] = __builtin_amdgcn_mfma_f32_16x16x32_bf16(wkf[kt][mt], xf[nt][kt], ka[mt][nt], 0, 0, 0);
            #pragma unroll
            for (int mt = 0; mt < 4; ++mt)
                #pragma unroll
                for (int nt = 0; nt < 3; ++nt)
                    pack4(&S[(j + 16 * nt) * P + 16 * mt + 4 * g], ka[mt][nt]);  // K[field][dim]
            __syncthreads();
        }

        // ---- K fragments for BOTH heads (before S is overwritten by Pt) ----
        s16x8 kA[2][3];
        #pragma unroll
        for (int h = 0; h < 2; ++h)
            #pragma unroll
            for (int t = 0; t < 3; ++t)
                kA[h][t] = *(const s16x8*)&S[(j + 16 * t) * P + 32 * h + 8 * g];
        __syncthreads();

        f32x4 oa[2][2][3];   // [h][md][nt]
        #pragma unroll
        for (int h = 0; h < 2; ++h) {
            // ---- issue this head's WV frag loads early (covered by scores+softmax) ----
            s16x8 wvf[2][2];   // [kt][md]
            #pragma unroll
            for (int kt = 0; kt < 2; ++kt)
                #pragma unroll
                for (int md = 0; md < 2; ++md)
                    wvf[kt][md] = *(const s16x8*)&wv[(j + 16 * (2 * h + md)) * E + 8 * g + 32 * kt];

            // ---- scores: S^T = K_h @ Q_h^T ----
            f32x4 sc[3][3];
            #pragma unroll
            for (int mt = 0; mt < 3; ++mt)
                #pragma unroll
                for (int nt = 0; nt < 3; ++nt)
                    sc[mt][nt] = __builtin_amdgcn_mfma_f32_16x16x32_bf16(kA[h][mt], qB[h][nt], (f32x4)0.f, 0, 0, 0);

            // ---- softmax over keys (raw-max, scale folded into exp arg; mask only mt==2) ----
            #pragma unroll
            for (int nt = 0; nt < 3; ++nt) {
                float mx = -1e30f;
                #pragma unroll
                for (int mt = 0; mt < 2; ++mt)
                    #pragma unroll
                    for (int r = 0; r < 4; ++r) mx = fmaxf(mx, sc[mt][nt][r]);
                #pragma unroll
                for (int r = 0; r < 4; ++r) {
                    int key = 32 + 4 * g + r;
                    float v = (key < F) ? sc[2][nt][r] : -1e30f;
                    sc[2][nt][r] = v;
                    mx = fmaxf(mx, v);
                }
                mx = fmaxf(mx, __shfl_xor(mx, 16));
                mx = fmaxf(mx, __shfl_xor(mx, 32));
                float mxs = mx * scale;
                float sum = 0.f;
                #pragma unroll
                for (int mt = 0; mt < 3; ++mt)
                    #pragma unroll
                    for (int r = 0; r < 4; ++r) {
                        float e = __expf(fmaf(sc[mt][nt][r], scale, -mxs));
                        sc[mt][nt][r] = e;
                        sum += e;
                    }
                sum += __shfl_xor(sum, 16);
                sum += __shfl_xor(sum, 32);
                float inv = 1.f / sum;
                #pragma unroll
                for (int mt = 0; mt < 3; ++mt)
                    #pragma unroll
                    for (int r = 0; r < 4; ++r) sc[mt][nt][r] *= inv;
            }

            // ---- this head's half-V: V = x @ WV^T (after softmax -> wvf loads covered) ----
            f32x4 va[3][2];
            #pragma unroll
            for (int mt = 0; mt < 3; ++mt)
                #pragma unroll
                for (int md = 0; md < 2; ++md) va[mt][md] = (f32x4)0.f;
            #pragma unroll
            for (int kt = 0; kt < 2; ++kt)
                #pragma unroll
                for (int md = 0; md < 2; ++md)
                    #pragma unroll
                    for (int mt = 0; mt < 3; ++mt)
                        va[mt][md] = __builtin_amdgcn_mfma_f32_16x16x32_bf16(xf[mt][kt], wvf[kt][md], va[mt][md], 0, 0, 0);

            // ---- stage Pt (zero key-pad 48..63) + this head's half-V ----
            #pragma unroll
            for (int nt = 0; nt < 3; ++nt) {
                #pragma unroll
                for (int mt = 0; mt < 3; ++mt)
                    pack4(&S[(16 * nt + j) * P + 16 * mt + 4 * g], sc[mt][nt]);
                *(ushort4*)&S[(16 * nt + j) * P + 48 + 4 * g] = z4;
            }
            #pragma unroll
            for (int md = 0; md < 2; ++md)
                #pragma unroll
                for (int mt = 0; mt < 3; ++mt)
                    pack4(&Vh[(j + 16 * md) * VP + 16 * mt + 4 * g], va[mt][md]);  // Vh[dim-in-head][key]
            __syncthreads();

            // ---- pb read, PV: out^T = V_h^T @ P_h^T ----
            s16x8 pb[2][3];
            #pragma unroll
            for (int kt = 0; kt < 2; ++kt)
                #pragma unroll
                for (int nt = 0; nt < 3; ++nt)
                    pb[kt][nt] = *(const s16x8*)&S[(j + 16 * nt) * P + 8 * g + 32 * kt];
            #pragma unroll
            for (int md = 0; md < 2; ++md)
                #pragma unroll
                for (int nt = 0; nt < 3; ++nt) oa[h][md][nt] = (f32x4)0.f;
            #pragma unroll
            for (int kt = 0; kt < 2; ++kt)
                #pragma unroll
                for (int md = 0; md < 2; ++md) {
                    s16x8 va2 = *(const s16x8*)&Vh[(j + 16 * md) * VP + 8 * g + 32 * kt];
                    #pragma unroll
                    for (int nt = 0; nt < 3; ++nt)
                        oa[h][md][nt] = __builtin_amdgcn_mfma_f32_16x16x32_bf16(va2, pb[kt][nt], oa[h][md][nt], 0, 0, 0);
                }
            __syncthreads();   // S + Vh reads done before next h overwrites
        }

        // ---- stage Ot[q][dim] (both heads) ----
        #pragma unroll
        for (int h = 0; h < 2; ++h)
            #pragma unroll
            for (int md = 0; md < 2; ++md)
                #pragma unroll
                for (int nt = 0; nt < 3; ++nt)
                    pack4(&S[(16 * nt + j) * P + 32 * h + 16 * md + 4 * g], oa[h][md][nt]);
        __syncthreads();

        // ---- next x^T = WO @ out^T + WR @ x^T (wo batch-issued, wr issued behind ob reads) ----
        {
            s16x8 wof[2][4];
            #pragma unroll
            for (int kt = 0; kt < 2; ++kt)
                #pragma unroll
                for (int mt = 0; mt < 4; ++mt)
                    wof[kt][mt] = *(const s16x8*)&wo[(j + 16 * mt) * E + 8 * g + 32 * kt];
            s16x8 ob[2][3];
            #pragma unroll
            for (int kt = 0; kt < 2; ++kt)
                #pragma unroll
                for (int nt = 0; nt < 3; ++nt)
                    ob[kt][nt] = *(const s16x8*)&S[(j + 16 * nt) * P + 8 * g + 32 * kt];
            s16x8 wrf[2][4];
            #pragma unroll
            for (int kt = 0; kt < 2; ++kt)
                #pragma unroll
                for (int mt = 0; mt < 4; ++mt)
                    wrf[kt][mt] = *(const s16x8*)&wr[(j + 16 * mt) * E + 8 * g + 32 * kt];

            f32x4 na[4][3];
            #pragma unroll
            for (int mt = 0; mt < 4; ++mt)
                #pragma unroll
                for (int nt = 0; nt < 3; ++nt) na[mt][nt] = (f32x4)0.f;
            #pragma unroll
            for (int kt = 0; kt < 2; ++kt)
                #pragma unroll
                for (int mt = 0; mt < 4; ++mt)
                    #pragma unroll
                    for (int nt = 0; nt < 3; ++nt)
                        na[mt][nt] = __builtin_amdgcn_mfma_f32_16x16x32_bf16(wof[kt][mt], ob[kt][nt], na[mt][nt], 0, 0, 0);
            #pragma unroll
            for (int kt = 0; kt < 2; ++kt)
                #pragma unroll
                for (int mt = 0; mt < 4; ++mt)
                    #pragma unroll
                    for (int nt = 0; nt < 3; ++nt)
                        na[mt][nt] = __builtin_amdgcn_mfma_f32_16x16x32_bf16(wrf[kt][mt], xf[nt][kt], na[mt][nt], 0, 0, 0);
            __syncthreads();
            #pragma unroll
            for (int mt = 0; mt < 4; ++mt)
                #pragma unroll
                for (int nt = 0; nt < 3; ++nt)
                    pack4(&S[(16 * nt + j) * P + 16 * mt + 4 * g], na[mt][nt]);  // x'[field][dim]
            __syncthreads();
            #pragma unroll
            for (int nt = 0; nt < 3; ++nt)
                #pragma unroll
                for (int kt = 0; kt < 2; ++kt)
                    xf[nt][kt] = *(const s16x8*)&S[(j + 16 * nt) * P + 8 * g + 32 * kt];
        }
    }

    // ---------------- final linear + sigmoid ----------------
    float acc = 0.f;
    for (int f = 0; f < F; ++f)
        acc += bf2f(S[f * P + l]) * Wf[f * E + l];
    #pragma unroll
    for (int off = 32; off > 0; off >>= 1) acc += __shfl_down(acc, off);
    if (l == 0) out[s] = 1.f / (1.f + __expf(-(acc + bfin[0])));
}

extern "C" void kernel_launch(void* const* d_in, const int* in_sizes, int n_in,
                              void* d_out, int out_size, void* d_ws, size_t ws_size,
                              hipStream_t stream) {
    ushort* wsb = (ushort*)d_ws;   // 61440 ushorts = 122880 B of scratch
    cvt_weights<<<240, 256, 0, stream>>>(
        (const float*)d_in[5], (const float*)d_in[6], (const float*)d_in[7],
        (const float*)d_in[8], (const float*)d_in[9], wsb);
    autoint_mfma<<<16384, 64, 0, stream>>>(
        (const float*)d_in[0], (const int*)d_in[1],
        (const float*)d_in[2], (const float*)d_in[3],
        (const float*)d_in[4], wsb,
        (const float*)d_in[10], (const float*)d_in[11],
        (float*)d_out);
}